// Round 1
// baseline (257.055 us; speedup 1.0000x reference)
//
#include <hip/hip_runtime.h>
#include <math.h>

#define BATCH 32768
#define NCLS  1000
#define NVEC  250          // 1000 / 4 float4s per row
#define SCALE 30.0f

__global__ __launch_bounds__(256) void ldam_kernel(
    const float* __restrict__ logits,
    const float* __restrict__ margins,
    const int*   __restrict__ targets,
    float*       __restrict__ out)
{
    const int wave = threadIdx.x >> 6;      // 0..3
    const int lane = threadIdx.x & 63;
    const int row  = blockIdx.x * 4 + wave; // one wave per row

    const int   t  = targets[row];
    const float mt = margins[t];
    const float* rowp = logits + (size_t)row * NCLS;
    const float4* rowv = (const float4*)rowp;

    // Load up to 4 float4 per lane, apply margin at target component, scale.
    float s[16];
    #pragma unroll
    for (int j = 0; j < 4; ++j) {
        const int idx = lane + 64 * j;      // float4 index within row
        float4 v;
        if (idx < NVEC) {
            v = rowv[idx];
            const int base = 4 * idx;
            if (base + 0 == t) v.x -= mt;
            if (base + 1 == t) v.y -= mt;
            if (base + 2 == t) v.z -= mt;
            if (base + 3 == t) v.w -= mt;
        } else {
            v = make_float4(-INFINITY, -INFINITY, -INFINITY, -INFINITY);
        }
        s[4*j + 0] = SCALE * v.x;
        s[4*j + 1] = SCALE * v.y;
        s[4*j + 2] = SCALE * v.z;
        s[4*j + 3] = SCALE * v.w;
    }

    // Per-lane max then sum of exp(s - m). exp(-inf) -> 0 for padding lanes.
    float m = s[0];
    #pragma unroll
    for (int k = 1; k < 16; ++k) m = fmaxf(m, s[k]);
    float l = 0.0f;
    #pragma unroll
    for (int k = 0; k < 16; ++k) l += __expf(s[k] - m);

    // Wave-wide butterfly merge of (m, l) pairs across 64 lanes.
    #pragma unroll
    for (int off = 1; off < 64; off <<= 1) {
        const float m2 = __shfl_xor(m, off);
        const float l2 = __shfl_xor(l, off);
        const float mn = fmaxf(m, m2);
        l = l * __expf(m - mn) + l2 * __expf(m2 - mn);
        m = mn;
    }

    // nll = logsumexp - s_target  (broadcast scalar load of logits[row, t])
    const float st  = SCALE * (rowp[t] - mt);
    const float nll = (m + __logf(l)) - st;

    __shared__ float partial[4];
    if (lane == 0) partial[wave] = nll;
    __syncthreads();
    if (threadIdx.x == 0) {
        const float sum = partial[0] + partial[1] + partial[2] + partial[3];
        atomicAdd(out, sum * (1.0f / (float)BATCH));
    }
}

extern "C" void kernel_launch(void* const* d_in, const int* in_sizes, int n_in,
                              void* d_out, int out_size, void* d_ws, size_t ws_size,
                              hipStream_t stream) {
    const float* logits  = (const float*)d_in[0];
    const float* margins = (const float*)d_in[1];
    const int*   targets = (const int*)d_in[2];
    float* out = (float*)d_out;

    hipMemsetAsync(out, 0, sizeof(float), stream);
    ldam_kernel<<<BATCH / 4, 256, 0, stream>>>(logits, margins, targets, out);
}

// Round 2
// 188.406 us; speedup vs baseline: 1.3644x; 1.3644x over previous
//
#include <hip/hip_runtime.h>
#include <math.h>

#define BATCH 32768
#define NCLS  1000
#define NVEC  250          // 1000 / 4 float4s per row
#define SCALE 30.0f
#define NBLOCKS (BATCH / 4) // 8192 blocks, 4 rows (waves) per block

__global__ __launch_bounds__(256) void ldam_kernel(
    const float* __restrict__ logits,
    const float* __restrict__ margins,
    const int*   __restrict__ targets,
    float*       __restrict__ partials)
{
    const int wave = threadIdx.x >> 6;      // 0..3
    const int lane = threadIdx.x & 63;
    const int row  = blockIdx.x * 4 + wave; // one wave per row

    const int   t  = targets[row];
    const float mt = margins[t];
    const float* rowp = logits + (size_t)row * NCLS;
    const float4* rowv = (const float4*)rowp;

    // Load up to 4 float4 per lane, apply margin at target component, scale.
    float s[16];
    #pragma unroll
    for (int j = 0; j < 4; ++j) {
        const int idx = lane + 64 * j;      // float4 index within row
        float4 v;
        if (idx < NVEC) {
            v = rowv[idx];
            const int base = 4 * idx;
            if (base + 0 == t) v.x -= mt;
            if (base + 1 == t) v.y -= mt;
            if (base + 2 == t) v.z -= mt;
            if (base + 3 == t) v.w -= mt;
        } else {
            v = make_float4(-INFINITY, -INFINITY, -INFINITY, -INFINITY);
        }
        s[4*j + 0] = SCALE * v.x;
        s[4*j + 1] = SCALE * v.y;
        s[4*j + 2] = SCALE * v.z;
        s[4*j + 3] = SCALE * v.w;
    }

    // Per-lane max then sum of exp(s - m). exp(-inf) -> 0 for padding lanes.
    float m = s[0];
    #pragma unroll
    for (int k = 1; k < 16; ++k) m = fmaxf(m, s[k]);
    float l = 0.0f;
    #pragma unroll
    for (int k = 0; k < 16; ++k) l += __expf(s[k] - m);

    // Wave-wide butterfly merge of (m, l) pairs across 64 lanes.
    #pragma unroll
    for (int off = 1; off < 64; off <<= 1) {
        const float m2 = __shfl_xor(m, off);
        const float l2 = __shfl_xor(l, off);
        const float mn = fmaxf(m, m2);
        l = l * __expf(m - mn) + l2 * __expf(m2 - mn);
        m = mn;
    }

    // nll = logsumexp - s_target  (broadcast scalar load; row is L1/L2 hot)
    const float st  = SCALE * (rowp[t] - mt);
    const float nll = (m + __logf(l)) - st;

    __shared__ float partial[4];
    if (lane == 0) partial[wave] = nll;
    __syncthreads();
    if (threadIdx.x == 0) {
        partials[blockIdx.x] = partial[0] + partial[1] + partial[2] + partial[3];
    }
}

// Single-block reduction of NBLOCKS partials -> mean in out[0].
__global__ __launch_bounds__(256) void ldam_reduce_kernel(
    const float* __restrict__ partials,
    float*       __restrict__ out)
{
    const int tid  = threadIdx.x;
    const int lane = tid & 63;
    const int wave = tid >> 6;

    // 8192 floats = 2048 float4s; 256 threads * 8 float4 each.
    const float4* pv = (const float4*)partials;
    float sum = 0.0f;
    #pragma unroll
    for (int j = 0; j < 8; ++j) {
        const float4 v = pv[tid + 256 * j];
        sum += (v.x + v.y) + (v.z + v.w);
    }

    // Wave butterfly sum.
    #pragma unroll
    for (int off = 1; off < 64; off <<= 1)
        sum += __shfl_xor(sum, off);

    __shared__ float ws[4];
    if (lane == 0) ws[wave] = sum;
    __syncthreads();
    if (tid == 0) {
        const float total = ws[0] + ws[1] + ws[2] + ws[3];
        out[0] = total * (1.0f / (float)BATCH);
    }
}

extern "C" void kernel_launch(void* const* d_in, const int* in_sizes, int n_in,
                              void* d_out, int out_size, void* d_ws, size_t ws_size,
                              hipStream_t stream) {
    const float* logits  = (const float*)d_in[0];
    const float* margins = (const float*)d_in[1];
    const int*   targets = (const int*)d_in[2];
    float* out      = (float*)d_out;
    float* partials = (float*)d_ws;

    ldam_kernel<<<NBLOCKS, 256, 0, stream>>>(logits, margins, targets, partials);
    ldam_reduce_kernel<<<1, 256, 0, stream>>>(partials, out);
}